// Round 14
// baseline (648.657 us; speedup 1.0000x reference)
//
#include <hip/hip_runtime.h>
#include <hip/hip_bf16.h>
#include <stdint.h>

typedef __hip_bfloat16 bf16_t;
typedef __attribute__((ext_vector_type(8))) short bf16x8;   // 8 bf16 = 4 VGPR
typedef __attribute__((ext_vector_type(4))) float f32x4;

#define DEV static __device__ __forceinline__

constexpr int kBB = 8, kL = 2048, kD = 1024;
constexpr int kM = kBB * kL;   // 16384 rows
constexpr int kSeg = 32, kP = 64;   // WKV: 32 segments x 64 steps

DEV float bf2f(unsigned short u) { return __uint_as_float((unsigned)u << 16); }
DEV unsigned short f2bf(float f) {
  unsigned u = __float_as_uint(f);
  return (unsigned short)((u + 0x7fffu + ((u >> 16) & 1u)) >> 16);  // RNE
}

// async global->LDS, 16B per lane. LDS dest is wave-uniform-base + lane*16.
DEV void gld16(const void* g, void* l) {
  const __attribute__((address_space(1))) unsigned* gp =
      (const __attribute__((address_space(1))) unsigned*)(uintptr_t)g;
  __attribute__((address_space(3))) unsigned* lp =
      (__attribute__((address_space(3))) unsigned*)(unsigned)(uintptr_t)l;
  __builtin_amdgcn_global_load_lds(gp, lp, 16, 0, 0);
}

// ------- batched weight transpose + cast (five 1024x1024): W[R][C] f32 -> Wt[C][R] bf16 -------
__global__ __launch_bounds__(256) void k_transpose5(
    const float* __restrict__ W0, const float* __restrict__ W1, const float* __restrict__ W2,
    const float* __restrict__ W3, const float* __restrict__ W4,
    bf16_t* __restrict__ T0, bf16_t* __restrict__ T1, bf16_t* __restrict__ T2,
    bf16_t* __restrict__ T3, bf16_t* __restrict__ T4) {
  const float* W; bf16_t* Wt;
  switch (blockIdx.z) {
    case 0: W = W0; Wt = T0; break;
    case 1: W = W1; Wt = T1; break;
    case 2: W = W2; Wt = T2; break;
    case 3: W = W3; Wt = T3; break;
    default: W = W4; Wt = T4; break;
  }
  __shared__ float tile[32][33];
  const int bx = blockIdx.x * 32, by = blockIdx.y * 32;
  const int tx = threadIdx.x & 31, ty = threadIdx.x >> 5;
#pragma unroll
  for (int i = 0; i < 32; i += 8)
    tile[ty + i][tx] = W[(size_t)(by + ty + i) * 1024 + (bx + tx)];
  __syncthreads();
#pragma unroll
  for (int i = 0; i < 32; i += 8)
    Wt[(size_t)(bx + ty + i) * 1024 + (by + tx)] = __float2bfloat16(tile[tx][ty + i]);
}

// ---------------- weight transpose + cast: W[R][C] f32 -> Wt[C][R] bf16 ---------------
__global__ __launch_bounds__(256) void k_transpose_cast(
    const float* __restrict__ W, bf16_t* __restrict__ Wt, int R, int C) {
  __shared__ float tile[32][33];
  const int bx = blockIdx.x * 32;
  const int by = blockIdx.y * 32;
  const int tx = threadIdx.x & 31, ty = threadIdx.x >> 5;
#pragma unroll
  for (int i = 0; i < 32; i += 8)
    tile[ty + i][tx] = W[(size_t)(by + ty + i) * C + (bx + tx)];
  __syncthreads();
#pragma unroll
  for (int i = 0; i < 32; i += 8)
    Wt[(size_t)(bx + ty + i) * R + (by + tx)] = __float2bfloat16(tile[tx][ty + i]);
}

// -------- fused LN(+stats)+shift+time-mix -> xk/xv/xr (bf16); one block per row --------
__global__ __launch_bounds__(256) void k_ln1f(
    const float* __restrict__ X, const float* __restrict__ g, const float* __restrict__ be,
    const float* __restrict__ mk, const float* __restrict__ mv, const float* __restrict__ mr,
    bf16_t* __restrict__ ok, bf16_t* __restrict__ ov, bf16_t* __restrict__ orr) {
  const int row = blockIdx.x;
  const int l = row & (kL - 1);
  const int i = threadIdx.x;                 // 4 floats per thread
  const bool hp = (l != 0);
  float xa[4], pa[4] = {0.f, 0.f, 0.f, 0.f};
  *(float4*)xa = ((const float4*)(X + (size_t)row * kD))[i];
  if (hp) *(float4*)pa = ((const float4*)(X + (size_t)(row - 1) * kD))[i];
  float s0 = xa[0] + xa[1] + xa[2] + xa[3];
  float q0 = xa[0] * xa[0] + xa[1] * xa[1] + xa[2] * xa[2] + xa[3] * xa[3];
  float s1 = pa[0] + pa[1] + pa[2] + pa[3];
  float q1 = pa[0] * pa[0] + pa[1] * pa[1] + pa[2] * pa[2] + pa[3] * pa[3];
#pragma unroll
  for (int off = 32; off > 0; off >>= 1) {
    s0 += __shfl_xor(s0, off); q0 += __shfl_xor(q0, off);
    s1 += __shfl_xor(s1, off); q1 += __shfl_xor(q1, off);
  }
  __shared__ float red[4][4];
  const int wid = i >> 6, lane = i & 63;
  if (lane == 0) { red[wid][0] = s0; red[wid][1] = q0; red[wid][2] = s1; red[wid][3] = q1; }
  __syncthreads();
  s0 = red[0][0] + red[1][0] + red[2][0] + red[3][0];
  q0 = red[0][1] + red[1][1] + red[2][1] + red[3][1];
  s1 = red[0][2] + red[1][2] + red[2][2] + red[3][2];
  q1 = red[0][3] + red[1][3] + red[2][3] + red[3][3];
  const float m0 = s0 * (1.f / kD);
  const float r0 = rsqrtf(fmaxf(q0 * (1.f / kD) - m0 * m0, 0.f) + 1e-5f);
  const float m1 = s1 * (1.f / kD);
  const float r1 = rsqrtf(fmaxf(q1 * (1.f / kD) - m1 * m1, 0.f) + 1e-5f);
  float ga[4], ba[4], ka[4], va[4], ra[4];
  *(float4*)ga = ((const float4*)g)[i];
  *(float4*)ba = ((const float4*)be)[i];
  *(float4*)ka = ((const float4*)mk)[i];
  *(float4*)va = ((const float4*)mv)[i];
  *(float4*)ra = ((const float4*)mr)[i];
  ushort4 uk, uv, ur;
  unsigned short* pk = (unsigned short*)&uk;
  unsigned short* pv = (unsigned short*)&uv;
  unsigned short* pr = (unsigned short*)&ur;
#pragma unroll
  for (int c = 0; c < 4; ++c) {
    float xn = (xa[c] - m0) * r0 * ga[c] + ba[c];
    float xp = hp ? (pa[c] - m1) * r1 * ga[c] + ba[c] : 0.f;   // shift: row 0 -> zeros
    pk[c] = f2bf(xn * ka[c] + xp * (1.f - ka[c]));
    pv[c] = f2bf(xn * va[c] + xp * (1.f - va[c]));
    pr[c] = f2bf(xn * ra[c] + xp * (1.f - ra[c]));
  }
  ((ushort4*)(ok + (size_t)row * kD))[i] = uk;
  ((ushort4*)(ov + (size_t)row * kD))[i] = uv;
  ((ushort4*)(orr + (size_t)row * kD))[i] = ur;
}

// ---- fused LN(+stats)+shift for channel mix, bf16 input x1: ymix=0.5(yn+yp), ynb=yn ----
__global__ __launch_bounds__(256) void k_ln2fb(
    const bf16_t* __restrict__ X, const float* __restrict__ g, const float* __restrict__ be,
    bf16_t* __restrict__ om, bf16_t* __restrict__ on) {
  const int row = blockIdx.x;
  const int l = row & (kL - 1);
  const int i = threadIdx.x;
  const bool hp = (l != 0);
  ushort4 xu = ((const ushort4*)(X + (size_t)row * kD))[i];
  ushort4 pu = make_ushort4(0, 0, 0, 0);
  if (hp) pu = ((const ushort4*)(X + (size_t)(row - 1) * kD))[i];
  float xa[4], pa[4];
  xa[0] = bf2f(xu.x); xa[1] = bf2f(xu.y); xa[2] = bf2f(xu.z); xa[3] = bf2f(xu.w);
  pa[0] = bf2f(pu.x); pa[1] = bf2f(pu.y); pa[2] = bf2f(pu.z); pa[3] = bf2f(pu.w);
  float s0 = xa[0] + xa[1] + xa[2] + xa[3];
  float q0 = xa[0] * xa[0] + xa[1] * xa[1] + xa[2] * xa[2] + xa[3] * xa[3];
  float s1 = pa[0] + pa[1] + pa[2] + pa[3];
  float q1 = pa[0] * pa[0] + pa[1] * pa[1] + pa[2] * pa[2] + pa[3] * pa[3];
#pragma unroll
  for (int off = 32; off > 0; off >>= 1) {
    s0 += __shfl_xor(s0, off); q0 += __shfl_xor(q0, off);
    s1 += __shfl_xor(s1, off); q1 += __shfl_xor(q1, off);
  }
  __shared__ float red[4][4];
  const int wid = i >> 6, lane = i & 63;
  if (lane == 0) { red[wid][0] = s0; red[wid][1] = q0; red[wid][2] = s1; red[wid][3] = q1; }
  __syncthreads();
  s0 = red[0][0] + red[1][0] + red[2][0] + red[3][0];
  q0 = red[0][1] + red[1][1] + red[2][1] + red[3][1];
  s1 = red[0][2] + red[1][2] + red[2][2] + red[3][2];
  q1 = red[0][3] + red[1][3] + red[2][3] + red[3][3];
  const float m0 = s0 * (1.f / kD);
  const float r0 = rsqrtf(fmaxf(q0 * (1.f / kD) - m0 * m0, 0.f) + 1e-5f);
  const float m1 = s1 * (1.f / kD);
  const float r1 = rsqrtf(fmaxf(q1 * (1.f / kD) - m1 * m1, 0.f) + 1e-5f);
  float ga[4], ba[4];
  *(float4*)ga = ((const float4*)g)[i];
  *(float4*)ba = ((const float4*)be)[i];
  ushort4 um, un;
  unsigned short* qm = (unsigned short*)&um;
  unsigned short* qn = (unsigned short*)&un;
#pragma unroll
  for (int c = 0; c < 4; ++c) {
    float yn = (xa[c] - m0) * r0 * ga[c] + ba[c];
    float yp = hp ? (pa[c] - m1) * r1 * ga[c] + ba[c] : 0.f;
    qm[c] = f2bf(0.5f * (yn + yp));
    qn[c] = f2bf(yn);
  }
  ((ushort4*)(om + (size_t)row * kD))[i] = um;
  ((ushort4*)(on + (size_t)row * kD))[i] = un;
}

// ===================== WKV: segmented parallel scan over L =====================
__global__ __launch_bounds__(256) void k_wkv_seg(
    const unsigned short* __restrict__ kq, const unsigned short* __restrict__ vq,
    const float* __restrict__ td, const float* __restrict__ tf,
    float* __restrict__ segA, float* __restrict__ segB) {
  const int d = blockIdx.x * 256 + threadIdx.x;
  const int b = blockIdx.y;
  const int s = blockIdx.z;
  const float ew = __expf(-__expf(td[d]));
  const float uu = (s == 0) ? tf[d] : 0.f;
  const size_t base = ((size_t)b * kL + (size_t)s * kP) * kD + d;
  float a = 0.f, bb = 0.f;
  unsigned short kA[16], vA[16], kB[16], vB[16];
  auto pref = [&](unsigned short* ka, unsigned short* va, int c) {
    const size_t o0 = base + (size_t)c * 16 * kD;
#pragma unroll
    for (int j = 0; j < 16; ++j) {
      ka[j] = kq[o0 + (size_t)j * kD];
      va[j] = vq[o0 + (size_t)j * kD];
    }
  };
  auto comp = [&](const unsigned short* ka, const unsigned short* va, int c) {
#pragma unroll
    for (int j = 0; j < 16; ++j) {
      float kf = bf2f(ka[j]);
      if (s == 0 && c == 0 && j == 0) kf += uu;    // t==0: exp(u + k0)
      float ek = __expf(kf);
      a = ew * a + ek * bf2f(va[j]);
      bb = ew * bb + ek;
    }
  };
  pref(kA, vA, 0);
  pref(kB, vB, 1); comp(kA, vA, 0);
  pref(kA, vA, 2); comp(kB, vB, 1);
  pref(kB, vB, 3); comp(kA, vA, 2);
  comp(kB, vB, 3);
  const size_t sidx = ((size_t)b * kSeg + s) * kD + d;
  segA[sidx] = a;
  segB[sidx] = bb;
}

__global__ __launch_bounds__(256) void k_wkv_carry(
    const float* __restrict__ td,
    const float* __restrict__ segA, const float* __restrict__ segB,
    float* __restrict__ carA, float* __restrict__ carB) {
  const int d = blockIdx.x * 256 + threadIdx.x;
  const int b = blockIdx.y;
  const float ew = __expf(-__expf(td[d]));
  float ewP = ew;
#pragma unroll
  for (int i = 0; i < 6; ++i) ewP *= ewP;          // ew^64
  float ca = 0.f, cb = 0.f;
#pragma unroll 4
  for (int s = 0; s < kSeg; ++s) {
    const size_t idx = ((size_t)b * kSeg + s) * kD + d;
    carA[idx] = ca;
    carB[idx] = cb;
    ca = ewP * ca + segA[idx];
    cb = ewP * cb + segB[idx];
  }
}

__global__ __launch_bounds__(256) void k_wkv_out(
    const unsigned short* __restrict__ kq, const unsigned short* __restrict__ vq,
    const unsigned short* __restrict__ rq, const float* __restrict__ td,
    const float* __restrict__ tf, const float* __restrict__ carA,
    const float* __restrict__ carB, unsigned short* __restrict__ out) {
  const int d = blockIdx.x * 256 + threadIdx.x;
  const int b = blockIdx.y;
  const int s = blockIdx.z;
  const float ew = __expf(-__expf(td[d]));
  const float uu = (s == 0) ? tf[d] : 0.f;
  const size_t base = ((size_t)b * kL + (size_t)s * kP) * kD + d;
  const size_t sidx = ((size_t)b * kSeg + s) * kD + d;
  float a = carA[sidx], bb = carB[sidx];
  unsigned short kA[16], vA[16], rA[16], kB[16], vB[16], rB[16];
  auto pref = [&](unsigned short* ka, unsigned short* va, unsigned short* ra, int c) {
    const size_t o0 = base + (size_t)c * 16 * kD;
#pragma unroll
    for (int j = 0; j < 16; ++j) {
      ka[j] = kq[o0 + (size_t)j * kD];
      va[j] = vq[o0 + (size_t)j * kD];
      ra[j] = rq[o0 + (size_t)j * kD];
    }
  };
  auto comp = [&](const unsigned short* ka, const unsigned short* va,
                  const unsigned short* ra, int c) {
    const size_t o0 = base + (size_t)c * 16 * kD;
#pragma unroll
    for (int j = 0; j < 16; ++j) {
      float kf = bf2f(ka[j]);
      if (s == 0 && c == 0 && j == 0) kf += uu;
      float ek = __expf(kf);
      a = ew * a + ek * bf2f(va[j]);
      bb = ew * bb + ek;
      float y = a / (bb + 1e-8f);
      float sr = 1.f / (1.f + __expf(-bf2f(ra[j])));
      out[o0 + (size_t)j * kD] = f2bf(sr * y);
    }
  };
  pref(kA, vA, rA, 0);
  pref(kB, vB, rB, 1); comp(kA, vA, rA, 0);
  pref(kA, vA, rA, 2); comp(kB, vB, rB, 1);
  pref(kB, vB, rB, 3); comp(kA, vA, rA, 2);
  comp(kB, vB, rB, 3);
}

// ====== gemmT: BM=BN=256 BK=64, 8 waves of 128x64, 16x16x32 (R8 loop, verified) ======
// 1 block/CU (128 KB LDS). Used for 256-block dispatches (Wo/Wfr/Wfv).
template <int EPI>
__global__ __launch_bounds__(512, 2) void gemmT(
    const bf16_t* __restrict__ A0, long strA, int lda,
    const bf16_t* __restrict__ B0, long strB, int ldb,
    bf16_t* __restrict__ Cb0, float* __restrict__ Cf, long strC,
    int N, int K, int nbx,
    const float* __restrict__ addf, const bf16_t* __restrict__ addb,
    const bf16_t* __restrict__ mulb) {
  __shared__ __align__(16) char lds[131072];
  const int z = blockIdx.z;
  const bf16_t* A = A0 + (size_t)z * strA;
  const bf16_t* Bt = B0 + (size_t)z * strB;
  const int nwg = gridDim.x;
  const int wg = (blockIdx.x & 7) * (nwg >> 3) + (blockIdx.x >> 3);
  const int by = wg / nbx, bx = wg - by * nbx;
  const long brow = (long)by * 256;
  const long bcol = (long)bx * 256;
  const int tid = threadIdx.x;
  const int lane = tid & 63;
  const int wid = tid >> 6;
  const int wr = wid >> 2, wc = wid & 3;

  f32x4 acc[8][4] = {};

  const int trow = tid >> 3;
  const int scol = ((tid & 7) * 16) ^ ((trow & 7) << 4);
  const char* Ag = (const char*)(A + (brow + trow) * (size_t)lda) + scol;
  const char* Bg = (const char*)(Bt + (bcol + trow) * (size_t)ldb) + scol;
  const long rsA = 64L * lda * 2;
  const long rsB = 64L * ldb * 2;

#define STAGE(kt, p)                                   \
  {                                                    \
    const long kb = (long)(kt) * 128;                  \
    char* Ld = lds + (p) * 65536 + tid * 16;           \
    gld16(Ag + kb, Ld);                                \
    gld16(Ag + kb + rsA, Ld + 8192);                   \
    gld16(Ag + kb + 2 * rsA, Ld + 16384);              \
    gld16(Ag + kb + 3 * rsA, Ld + 24576);              \
    gld16(Bg + kb, Ld + 32768);                        \
    gld16(Bg + kb + rsB, Ld + 40960);                  \
    gld16(Bg + kb + 2 * rsB, Ld + 49152);              \
    gld16(Bg + kb + 3 * rsB, Ld + 57344);              \
  }

  const int l16 = lane & 15, kq = lane >> 4;
  const int swz = (l16 & 7) << 4;
  const int oS0 = (kq * 16) ^ swz;
  const int oS1 = (64 + kq * 16) ^ swz;
  const char* Arow = lds + (wr * 128 + l16) * 128;
  const char* Brow = lds + 32768 + (wc * 64 + l16) * 128;

  bf16x8 aE[8], bE[4], aO[8], bO[4];
  const int NT = K >> 6;

  STAGE(0, 0) STAGE(1, 1)
  asm volatile("s_waitcnt vmcnt(8)" ::: "memory");
  __builtin_amdgcn_s_barrier();
#pragma unroll
  for (int m = 0; m < 8; ++m) aE[m] = *(const bf16x8*)(Arow + m * 2048 + oS0);
#pragma unroll
  for (int n = 0; n < 4; ++n) bE[n] = *(const bf16x8*)(Brow + n * 2048 + oS0);

  for (int t = 0; t < NT; ++t) {
    const int p = t & 1;
    const char* Ap = Arow + p * 65536;
    const char* Bp = Brow + p * 65536;
#pragma unroll
    for (int m = 0; m < 8; ++m) aO[m] = *(const bf16x8*)(Ap + m * 2048 + oS1);
#pragma unroll
    for (int n = 0; n < 4; ++n) bO[n] = *(const bf16x8*)(Bp + n * 2048 + oS1);
    __builtin_amdgcn_sched_barrier(0);
    __builtin_amdgcn_s_setprio(1);
#pragma unroll
    for (int m = 0; m < 8; ++m)
#pragma unroll
      for (int n = 0; n < 4; ++n)
        acc[m][n] = __builtin_amdgcn_mfma_f32_16x16x32_bf16(aE[m], bE[n], acc[m][n], 0, 0, 0);
    __builtin_amdgcn_s_setprio(0);
    asm volatile("s_waitcnt lgkmcnt(0)" ::: "memory");
    asm volatile("s_waitcnt vmcnt(0)" ::: "memory");
    __builtin_amdgcn_s_barrier();
    if (t + 2 < NT) STAGE(t + 2, p)
    if (t + 1 < NT) {
      const char* An = Arow + (1 - p) * 65536;
      const char* Bn = Brow + (1 - p) * 65536;
#pragma unroll
      for (int m = 0; m < 8; ++m) aE[m] = *(const bf16x8*)(An + m * 2048 + oS0);
#pragma unroll
      for (int n = 0; n < 4; ++n) bE[n] = *(const bf16x8*)(Bn + n * 2048 + oS0);
    }
    __builtin_amdgcn_sched_barrier(0);
    __builtin_amdgcn_s_setprio(1);
#pragma unroll
    for (int m = 0; m < 8; ++m)
#pragma unroll
      for (int n = 0; n < 4; ++n)
        acc[m][n] = __builtin_amdgcn_mfma_f32_16x16x32_bf16(aO[m], bO[n], acc[m][n], 0, 0, 0);
    __builtin_amdgcn_s_setprio(0);
  }
#undef STAGE

  bf16_t* Cb = Cb0 + (size_t)z * strC;
  const long orow = brow + wr * 128 + (lane >> 4) * 4;
  const long ocol = bcol + wc * 64 + l16;
#pragma unroll
  for (int m = 0; m < 8; ++m) {
#pragma unroll
    for (int reg = 0; reg < 4; ++reg) {
      const long r = orow + m * 16 + reg;
#pragma unroll
      for (int n = 0; n < 4; ++n) {
        const size_t idx = (size_t)r * N + ocol + n * 16;
        const float v = acc[m][n][reg];
        if constexpr (EPI == 0) {
          Cb[idx] = __float2bfloat16(v);
        } else if constexpr (EPI == 1) {
          Cb[idx] = __float2bfloat16(addf[idx] + v);
        } else if constexpr (EPI == 2) {
          float u = v > 0.f ? v : 0.f;
          Cb[idx] = __float2bfloat16(u * u);
        } else if constexpr (EPI == 3) {
          Cb[idx] = __float2bfloat16(1.f / (1.f + __expf(-v)));
        } else if constexpr (EPI == 4) {
          Cf[idx] = v;
        } else {
          Cf[idx] = __bfloat162float(addb[idx]) + __bfloat162float(mulb[idx]) * (Cf[idx] + v);
        }
      }
    }
  }
}

// ====== gemmS: BM=BN=256 BK=32, 8 waves of 128x64; 64 KB LDS -> 2 blocks/CU ======
// Cross-block overlap (m114/m97): co-resident block's MFMA fills this block's
// LDS-read/barrier gaps. Sync: exact vmcnt(0) in-loop; prologue vmcnt(4) safe
// (vm stream = only mutually-ordered global_load_lds, no plain global loads).
// Swizzle for 64B rows (4 slots): slot ^= (row>>1)&3  (<=4 lanes/granule).
// Buffer safety: reads of tile t issued at iter t-1 end are consumed by MFMA
// (reg dependency) before this wave passes the iter-t barrier; STAGE(t+2)->buf[t&1]
// issues after that barrier. Reads of buf[1-p] follow the barrier that vmcnt(0)'d
// STAGE(t+1). Used only for grids >=512 blocks (projections, Wfk).
template <int EPI>
__global__ __launch_bounds__(512, 2) void gemmS(
    const bf16_t* __restrict__ A0, long strA, int lda,
    const bf16_t* __restrict__ B0, long strB, int ldb,
    bf16_t* __restrict__ Cb0, long strC,
    int N, int K, int nbx) {
  __shared__ __align__(16) char lds[65536];   // 2 x (A[256][32]bf16 16KB + B 16KB)
  const int z = blockIdx.z;
  const bf16_t* A = A0 + (size_t)z * strA;
  const bf16_t* Bt = B0 + (size_t)z * strB;
  const int nwg = gridDim.x;
  const int wg = (blockIdx.x & 7) * (nwg >> 3) + (blockIdx.x >> 3);
  const int by = wg / nbx, bx = wg - by * nbx;
  const long brow = (long)by * 256;
  const long bcol = (long)bx * 256;
  const int tid = threadIdx.x;
  const int lane = tid & 63;
  const int wid = tid >> 6;
  const int wr = wid >> 2, wc = wid & 3;   // 2 x 4 waves, each 128x64 out

  f32x4 acc[8][4] = {};

  // staging: thread -> (row = tid>>2 within 128-row chunk, slot = tid&3)
  const int trow = tid >> 2;
  const int scol = ((tid & 3) * 16) ^ (((trow >> 1) & 3) << 4);  // pre-swizzled source
  const char* Ag = (const char*)(A + (brow + trow) * (size_t)lda) + scol;
  const char* Bg = (const char*)(Bt + (bcol + trow) * (size_t)ldb) + scol;
  const long rsA = 128L * lda * 2;   // +128 rows
  const long rsB = 128L * ldb * 2;

#define STAGE32(kt, p)                                 \
  {                                                    \
    const long kb = (long)(kt) * 64;                   \
    char* Ld = lds + (p) * 32768 + tid * 16;           \
    gld16(Ag + kb, Ld);                                \
    gld16(Ag + kb + rsA, Ld + 8192);                   \
    gld16(Bg + kb, Ld + 16384);                        \
    gld16(Bg + kb + rsB, Ld + 24576);                  \
  }

  // frag reads: row r (64B rows), byte-col c -> c ^ (((r>>1)&3)<<4); rows are
  // base16 + l16 with base16 % 16 == 0, so (r>>1)&3 == ((l16>>1)&3)
  const int l16 = lane & 15, kq = lane >> 4;
  const int oS = (kq * 16) ^ (((l16 >> 1) & 3) << 4);
  const int ArowO = (wr * 128 + l16) * 64;            // A frag m: +m*1024
  const int BrowO = 16384 + (wc * 64 + l16) * 64;     // B frag n: +n*1024

  bf16x8 aA[8], bA[4], aB[8], bB[4];
  const int NT = K >> 5;                               // even (K multiple of 64)

#define RDFRAG(AS, BS, p)                              \
  {                                                    \
    const char* Ar = lds + (p) * 32768 + ArowO;        \
    const char* Br = lds + (p) * 32768 + BrowO;        \
    _Pragma("unroll") for (int m = 0; m < 8; ++m)      \
      AS[m] = *(const bf16x8*)(Ar + m * 1024 + oS);    \
    _Pragma("unroll") for (int n = 0; n < 4; ++n)      \
      BS[n] = *(const bf16x8*)(Br + n * 1024 + oS);    \
  }

#define MFMA32(AS, BS)                                 \
  __builtin_amdgcn_s_setprio(1);                       \
  _Pragma("unroll") for (int m = 0; m < 8; ++m)        \
    _Pragma("unroll") for (int n = 0; n < 4; ++n)      \
      acc[m][n] = __builtin_amdgcn_mfma_f32_16x16x32_bf16(AS[m], BS[n], acc[m][n], 0, 0, 0); \
  __builtin_amdgcn_s_setprio(0);

  STAGE32(0, 0) STAGE32(1, 1)
  asm volatile("s_waitcnt vmcnt(4)" ::: "memory");   // tile0 landed (counted-safe)
  __builtin_amdgcn_s_barrier();
  RDFRAG(aA, bA, 0)

  for (int t = 0; t < NT; t += 2) {
    // even tile t: regs A, buf0
    MFMA32(aA, bA)                                   // consumes aA/bA (reads forced done)
    asm volatile("s_waitcnt vmcnt(0)" ::: "memory"); // STAGE32(t+1) landed
    __builtin_amdgcn_s_barrier();                    // all reads of buf0 done; buf1 ready
    if (t + 2 < NT) STAGE32(t + 2, 0)
    RDFRAG(aB, bB, 1)                                // frags(t+1)
    // odd tile t+1: regs B, buf1
    MFMA32(aB, bB)
    asm volatile("s_waitcnt vmcnt(0)" ::: "memory"); // STAGE32(t+2) landed (if issued)
    __builtin_amdgcn_s_barrier();
    if (t + 3 < NT) STAGE32(t + 3, 1)
    if (t + 2 < NT) RDFRAG(aA, bA, 0)
  }
#undef STAGE32
#undef RDFRAG
#undef MFMA32

  bf16_t* Cb = Cb0 + (size_t)z * strC;
  const long orow = brow + wr * 128 + (lane >> 4) * 4;
  const long ocol = bcol + wc * 64 + l16;
#pragma unroll
  for (int m = 0; m < 8; ++m) {
#pragma unroll
    for (int reg = 0; reg < 4; ++reg) {
      const long r = orow + m * 16 + reg;
#pragma unroll
      for (int n = 0; n < 4; ++n) {
        const size_t idx = (size_t)r * N + ocol + n * 16;
        const float v = acc[m][n][reg];
        if constexpr (EPI == 0) {
          Cb[idx] = __float2bfloat16(v);
        } else {   // EPI == 2: relu^2
          float u = v > 0.f ? v : 0.f;
          Cb[idx] = __float2bfloat16(u * u);
        }
      }
    }
  }
}

extern "C" void kernel_launch(void* const* d_in, const int* in_sizes, int n_in,
                              void* d_out, int out_size, void* d_ws, size_t ws_size,
                              hipStream_t stream) {
  const float* x    = (const float*)d_in[0];
  const float* ln1g = (const float*)d_in[1];
  const float* ln1b = (const float*)d_in[2];
  const float* Wk   = (const float*)d_in[3];
  const float* Wv   = (const float*)d_in[4];
  const float* Wr   = (const float*)d_in[5];
  const float* Wo   = (const float*)d_in[6];
  const float* td   = (const float*)d_in[7];
  const float* tf   = (const float*)d_in[8];
  const float* mk   = (const float*)d_in[9];
  const float* mv   = (const float*)d_in[10];
  const float* mr   = (const float*)d_in[11];
  const float* ln2g = (const float*)d_in[12];
  const float* ln2b = (const float*)d_in[13];
  const float* Wfk  = (const float*)d_in[14];
  const float* Wfv  = (const float*)d_in[15];
  const float* Wfr  = (const float*)d_in[16];

  char* ws = (char*)d_ws;
  const size_t MB = 1ull << 20;
  bf16_t* WkT  = (bf16_t*)(ws + 0 * MB);
  bf16_t* WvT  = (bf16_t*)(ws + 2 * MB);
  bf16_t* WrT  = (bf16_t*)(ws + 4 * MB);
  bf16_t* WoT  = (bf16_t*)(ws + 6 * MB);
  bf16_t* WfkT = (bf16_t*)(ws + 8 * MB);    // [4096][1024]
  bf16_t* WfvT = (bf16_t*)(ws + 16 * MB);   // [1024][4096]
  bf16_t* WfrT = (bf16_t*)(ws + 24 * MB);
  bf16_t* xk   = (bf16_t*)(ws + 28 * MB);
  bf16_t* xv   = (bf16_t*)(ws + 60 * MB);
  bf16_t* xr   = (bf16_t*)(ws + 92 * MB);
  bf16_t* kbuf = (bf16_t*)(ws + 124 * MB);
  bf16_t* vbuf = (bf16_t*)(ws + 156 * MB);
  bf16_t* rbuf = (bf16_t*)(ws + 188 * MB);
  float*  segA = (float*)(ws + 60 * MB);
  float*  segB = (float*)(ws + 61 * MB);
  float*  carA = (float*)(ws + 62 * MB);
  float*  carB = (float*)(ws + 63 * MB);
  bf16_t* rwkv = (bf16_t*)(ws + 92 * MB);
  bf16_t* x1b  = (bf16_t*)(ws + 28 * MB);   // bf16 residual, 32 MB
  bf16_t* rr   = (bf16_t*)(ws + 92 * MB);
  bf16_t* ynb  = (bf16_t*)(ws + 124 * MB);
  bf16_t* kk   = (bf16_t*)(ws + 124 * MB);  // [16384][2048] bf16 = 64 MB
  bf16_t* ymix = (bf16_t*)(ws + 188 * MB);
  float*  out  = (float*)d_out;
  const long sX = (long)kM * kD;
  const long sW = (long)kD * kD;

  dim3 blk(256), blkg(512);
  // weights -> bf16 B^T (five 1024^2 batched; Wfk/Wfv separate shapes)
  k_transpose5<<<dim3(32, 32, 5), blk, 0, stream>>>(Wk, Wv, Wr, Wo, Wfr,
                                                    WkT, WvT, WrT, WoT, WfrT);
  k_transpose_cast<<<dim3(128, 32), blk, 0, stream>>>(Wfk, WfkT, 1024, 4096);
  k_transpose_cast<<<dim3(32, 128), blk, 0, stream>>>(Wfv, WfvT, 4096, 1024);

  // ---- time mixing ----
  k_ln1f<<<kM, blk, 0, stream>>>(x, ln1g, ln1b, mk, mv, mr, xk, xv, xr);
  gemmS<0><<<dim3(256, 1, 3), blkg, 0, stream>>>(xk, sX, 1024, WkT, sW, 1024,
      kbuf, sX, 1024, 1024, 4);
  k_wkv_seg<<<dim3(4, 8, kSeg), blk, 0, stream>>>((const unsigned short*)kbuf,
      (const unsigned short*)vbuf, td, tf, segA, segB);
  k_wkv_carry<<<dim3(4, 8), blk, 0, stream>>>(td, segA, segB, carA, carB);
  k_wkv_out<<<dim3(4, 8, kSeg), blk, 0, stream>>>((const unsigned short*)kbuf,
      (const unsigned short*)vbuf, (const unsigned short*)rbuf, td, tf, carA, carB,
      (unsigned short*)rwkv);
  gemmT<1><<<256, blkg, 0, stream>>>(rwkv, 0, 1024, WoT, 0, 1024,
      x1b, nullptr, 0, 1024, 1024, 4, x, nullptr, nullptr);

  // ---- channel mixing ----
  k_ln2fb<<<kM, blk, 0, stream>>>(x1b, ln2g, ln2b, ymix, ynb);
  gemmT<3><<<256, blkg, 0, stream>>>(ynb, 0, 1024, WfrT, 0, 1024,
      rr, nullptr, 0, 1024, 1024, 4, nullptr, nullptr, nullptr);
  // hidden dim in 2 chunks of 2048: kk = relu(ymix@Wfk[:,c])^2; out (+)= kk@Wfv[c,:]
  for (int c = 0; c < 2; ++c) {
    gemmS<2><<<512, blkg, 0, stream>>>(ymix, 0, 1024, WfkT + (size_t)c * 2048 * 1024, 0, 1024,
        kk, 0, 2048, 1024, 8);
    if (c == 0)
      gemmT<4><<<256, blkg, 0, stream>>>(kk, 0, 2048, WfvT + 0, 0, 4096,
          nullptr, out, 0, 1024, 2048, 4, nullptr, nullptr, nullptr);
    else
      gemmT<6><<<256, blkg, 0, stream>>>(kk, 0, 2048, WfvT + 2048, 0, 4096,
          nullptr, out, 0, 1024, 2048, 4, nullptr, x1b, rr);
  }
}

// Round 15
// 619.737 us; speedup vs baseline: 1.0467x; 1.0467x over previous
//
#include <hip/hip_runtime.h>
#include <hip/hip_bf16.h>
#include <stdint.h>

typedef __hip_bfloat16 bf16_t;
typedef __attribute__((ext_vector_type(8))) short bf16x8;   // 8 bf16 = 4 VGPR
typedef __attribute__((ext_vector_type(4))) float f32x4;

#define DEV static __device__ __forceinline__

constexpr int kBB = 8, kL = 2048, kD = 1024;
constexpr int kM = kBB * kL;   // 16384 rows
constexpr int kSeg = 32, kP = 64;   // WKV: 32 segments x 64 steps

DEV float bf2f(unsigned short u) { return __uint_as_float((unsigned)u << 16); }
DEV unsigned short f2bf(float f) {
  unsigned u = __float_as_uint(f);
  return (unsigned short)((u + 0x7fffu + ((u >> 16) & 1u)) >> 16);  // RNE
}

// async global->LDS, 16B per lane. LDS dest is wave-uniform-base + lane*16.
DEV void gld16(const void* g, void* l) {
  const __attribute__((address_space(1))) unsigned* gp =
      (const __attribute__((address_space(1))) unsigned*)(uintptr_t)g;
  __attribute__((address_space(3))) unsigned* lp =
      (__attribute__((address_space(3))) unsigned*)(unsigned)(uintptr_t)l;
  __builtin_amdgcn_global_load_lds(gp, lp, 16, 0, 0);
}

// ------- batched weight transpose + cast (five 1024x1024): W[R][C] f32 -> Wt[C][R] bf16 -------
__global__ __launch_bounds__(256) void k_transpose5(
    const float* __restrict__ W0, const float* __restrict__ W1, const float* __restrict__ W2,
    const float* __restrict__ W3, const float* __restrict__ W4,
    bf16_t* __restrict__ T0, bf16_t* __restrict__ T1, bf16_t* __restrict__ T2,
    bf16_t* __restrict__ T3, bf16_t* __restrict__ T4) {
  const float* W; bf16_t* Wt;
  switch (blockIdx.z) {
    case 0: W = W0; Wt = T0; break;
    case 1: W = W1; Wt = T1; break;
    case 2: W = W2; Wt = T2; break;
    case 3: W = W3; Wt = T3; break;
    default: W = W4; Wt = T4; break;
  }
  __shared__ float tile[32][33];
  const int bx = blockIdx.x * 32, by = blockIdx.y * 32;
  const int tx = threadIdx.x & 31, ty = threadIdx.x >> 5;
#pragma unroll
  for (int i = 0; i < 32; i += 8)
    tile[ty + i][tx] = W[(size_t)(by + ty + i) * 1024 + (bx + tx)];
  __syncthreads();
#pragma unroll
  for (int i = 0; i < 32; i += 8)
    Wt[(size_t)(bx + ty + i) * 1024 + (by + tx)] = __float2bfloat16(tile[tx][ty + i]);
}

// ---------------- weight transpose + cast: W[R][C] f32 -> Wt[C][R] bf16 ---------------
__global__ __launch_bounds__(256) void k_transpose_cast(
    const float* __restrict__ W, bf16_t* __restrict__ Wt, int R, int C) {
  __shared__ float tile[32][33];
  const int bx = blockIdx.x * 32;
  const int by = blockIdx.y * 32;
  const int tx = threadIdx.x & 31, ty = threadIdx.x >> 5;
#pragma unroll
  for (int i = 0; i < 32; i += 8)
    tile[ty + i][tx] = W[(size_t)(by + ty + i) * C + (bx + tx)];
  __syncthreads();
#pragma unroll
  for (int i = 0; i < 32; i += 8)
    Wt[(size_t)(bx + ty + i) * R + (by + tx)] = __float2bfloat16(tile[tx][ty + i]);
}

// -------- fused LN(+stats)+shift+time-mix -> xk/xv/xr (bf16); one block per row --------
__global__ __launch_bounds__(256) void k_ln1f(
    const float* __restrict__ X, const float* __restrict__ g, const float* __restrict__ be,
    const float* __restrict__ mk, const float* __restrict__ mv, const float* __restrict__ mr,
    bf16_t* __restrict__ ok, bf16_t* __restrict__ ov, bf16_t* __restrict__ orr) {
  const int row = blockIdx.x;
  const int l = row & (kL - 1);
  const int i = threadIdx.x;                 // 4 floats per thread
  const bool hp = (l != 0);
  float xa[4], pa[4] = {0.f, 0.f, 0.f, 0.f};
  *(float4*)xa = ((const float4*)(X + (size_t)row * kD))[i];
  if (hp) *(float4*)pa = ((const float4*)(X + (size_t)(row - 1) * kD))[i];
  float s0 = xa[0] + xa[1] + xa[2] + xa[3];
  float q0 = xa[0] * xa[0] + xa[1] * xa[1] + xa[2] * xa[2] + xa[3] * xa[3];
  float s1 = pa[0] + pa[1] + pa[2] + pa[3];
  float q1 = pa[0] * pa[0] + pa[1] * pa[1] + pa[2] * pa[2] + pa[3] * pa[3];
#pragma unroll
  for (int off = 32; off > 0; off >>= 1) {
    s0 += __shfl_xor(s0, off); q0 += __shfl_xor(q0, off);
    s1 += __shfl_xor(s1, off); q1 += __shfl_xor(q1, off);
  }
  __shared__ float red[4][4];
  const int wid = i >> 6, lane = i & 63;
  if (lane == 0) { red[wid][0] = s0; red[wid][1] = q0; red[wid][2] = s1; red[wid][3] = q1; }
  __syncthreads();
  s0 = red[0][0] + red[1][0] + red[2][0] + red[3][0];
  q0 = red[0][1] + red[1][1] + red[2][1] + red[3][1];
  s1 = red[0][2] + red[1][2] + red[2][2] + red[3][2];
  q1 = red[0][3] + red[1][3] + red[2][3] + red[3][3];
  const float m0 = s0 * (1.f / kD);
  const float r0 = rsqrtf(fmaxf(q0 * (1.f / kD) - m0 * m0, 0.f) + 1e-5f);
  const float m1 = s1 * (1.f / kD);
  const float r1 = rsqrtf(fmaxf(q1 * (1.f / kD) - m1 * m1, 0.f) + 1e-5f);
  float ga[4], ba[4], ka[4], va[4], ra[4];
  *(float4*)ga = ((const float4*)g)[i];
  *(float4*)ba = ((const float4*)be)[i];
  *(float4*)ka = ((const float4*)mk)[i];
  *(float4*)va = ((const float4*)mv)[i];
  *(float4*)ra = ((const float4*)mr)[i];
  ushort4 uk, uv, ur;
  unsigned short* pk = (unsigned short*)&uk;
  unsigned short* pv = (unsigned short*)&uv;
  unsigned short* pr = (unsigned short*)&ur;
#pragma unroll
  for (int c = 0; c < 4; ++c) {
    float xn = (xa[c] - m0) * r0 * ga[c] + ba[c];
    float xp = hp ? (pa[c] - m1) * r1 * ga[c] + ba[c] : 0.f;   // shift: row 0 -> zeros
    pk[c] = f2bf(xn * ka[c] + xp * (1.f - ka[c]));
    pv[c] = f2bf(xn * va[c] + xp * (1.f - va[c]));
    pr[c] = f2bf(xn * ra[c] + xp * (1.f - ra[c]));
  }
  ((ushort4*)(ok + (size_t)row * kD))[i] = uk;
  ((ushort4*)(ov + (size_t)row * kD))[i] = uv;
  ((ushort4*)(orr + (size_t)row * kD))[i] = ur;
}

// ---- fused LN(+stats)+shift for channel mix, bf16 input x1: ymix=0.5(yn+yp), ynb=yn ----
__global__ __launch_bounds__(256) void k_ln2fb(
    const bf16_t* __restrict__ X, const float* __restrict__ g, const float* __restrict__ be,
    bf16_t* __restrict__ om, bf16_t* __restrict__ on) {
  const int row = blockIdx.x;
  const int l = row & (kL - 1);
  const int i = threadIdx.x;
  const bool hp = (l != 0);
  ushort4 xu = ((const ushort4*)(X + (size_t)row * kD))[i];
  ushort4 pu = make_ushort4(0, 0, 0, 0);
  if (hp) pu = ((const ushort4*)(X + (size_t)(row - 1) * kD))[i];
  float xa[4], pa[4];
  xa[0] = bf2f(xu.x); xa[1] = bf2f(xu.y); xa[2] = bf2f(xu.z); xa[3] = bf2f(xu.w);
  pa[0] = bf2f(pu.x); pa[1] = bf2f(pu.y); pa[2] = bf2f(pu.z); pa[3] = bf2f(pu.w);
  float s0 = xa[0] + xa[1] + xa[2] + xa[3];
  float q0 = xa[0] * xa[0] + xa[1] * xa[1] + xa[2] * xa[2] + xa[3] * xa[3];
  float s1 = pa[0] + pa[1] + pa[2] + pa[3];
  float q1 = pa[0] * pa[0] + pa[1] * pa[1] + pa[2] * pa[2] + pa[3] * pa[3];
#pragma unroll
  for (int off = 32; off > 0; off >>= 1) {
    s0 += __shfl_xor(s0, off); q0 += __shfl_xor(q0, off);
    s1 += __shfl_xor(s1, off); q1 += __shfl_xor(q1, off);
  }
  __shared__ float red[4][4];
  const int wid = i >> 6, lane = i & 63;
  if (lane == 0) { red[wid][0] = s0; red[wid][1] = q0; red[wid][2] = s1; red[wid][3] = q1; }
  __syncthreads();
  s0 = red[0][0] + red[1][0] + red[2][0] + red[3][0];
  q0 = red[0][1] + red[1][1] + red[2][1] + red[3][1];
  s1 = red[0][2] + red[1][2] + red[2][2] + red[3][2];
  q1 = red[0][3] + red[1][3] + red[2][3] + red[3][3];
  const float m0 = s0 * (1.f / kD);
  const float r0 = rsqrtf(fmaxf(q0 * (1.f / kD) - m0 * m0, 0.f) + 1e-5f);
  const float m1 = s1 * (1.f / kD);
  const float r1 = rsqrtf(fmaxf(q1 * (1.f / kD) - m1 * m1, 0.f) + 1e-5f);
  float ga[4], ba[4];
  *(float4*)ga = ((const float4*)g)[i];
  *(float4*)ba = ((const float4*)be)[i];
  ushort4 um, un;
  unsigned short* qm = (unsigned short*)&um;
  unsigned short* qn = (unsigned short*)&un;
#pragma unroll
  for (int c = 0; c < 4; ++c) {
    float yn = (xa[c] - m0) * r0 * ga[c] + ba[c];
    float yp = hp ? (pa[c] - m1) * r1 * ga[c] + ba[c] : 0.f;
    qm[c] = f2bf(0.5f * (yn + yp));
    qn[c] = f2bf(yn);
  }
  ((ushort4*)(om + (size_t)row * kD))[i] = um;
  ((ushort4*)(on + (size_t)row * kD))[i] = un;
}

// ===================== WKV: segmented parallel scan over L =====================
__global__ __launch_bounds__(256) void k_wkv_seg(
    const unsigned short* __restrict__ kq, const unsigned short* __restrict__ vq,
    const float* __restrict__ td, const float* __restrict__ tf,
    float* __restrict__ segA, float* __restrict__ segB) {
  const int d = blockIdx.x * 256 + threadIdx.x;
  const int b = blockIdx.y;
  const int s = blockIdx.z;
  const float ew = __expf(-__expf(td[d]));
  const float uu = (s == 0) ? tf[d] : 0.f;
  const size_t base = ((size_t)b * kL + (size_t)s * kP) * kD + d;
  float a = 0.f, bb = 0.f;
  unsigned short kA[16], vA[16], kB[16], vB[16];
  auto pref = [&](unsigned short* ka, unsigned short* va, int c) {
    const size_t o0 = base + (size_t)c * 16 * kD;
#pragma unroll
    for (int j = 0; j < 16; ++j) {
      ka[j] = kq[o0 + (size_t)j * kD];
      va[j] = vq[o0 + (size_t)j * kD];
    }
  };
  auto comp = [&](const unsigned short* ka, const unsigned short* va, int c) {
#pragma unroll
    for (int j = 0; j < 16; ++j) {
      float kf = bf2f(ka[j]);
      if (s == 0 && c == 0 && j == 0) kf += uu;    // t==0: exp(u + k0)
      float ek = __expf(kf);
      a = ew * a + ek * bf2f(va[j]);
      bb = ew * bb + ek;
    }
  };
  pref(kA, vA, 0);
  pref(kB, vB, 1); comp(kA, vA, 0);
  pref(kA, vA, 2); comp(kB, vB, 1);
  pref(kB, vB, 3); comp(kA, vA, 2);
  comp(kB, vB, 3);
  const size_t sidx = ((size_t)b * kSeg + s) * kD + d;
  segA[sidx] = a;
  segB[sidx] = bb;
}

__global__ __launch_bounds__(256) void k_wkv_carry(
    const float* __restrict__ td,
    const float* __restrict__ segA, const float* __restrict__ segB,
    float* __restrict__ carA, float* __restrict__ carB) {
  const int d = blockIdx.x * 256 + threadIdx.x;
  const int b = blockIdx.y;
  const float ew = __expf(-__expf(td[d]));
  float ewP = ew;
#pragma unroll
  for (int i = 0; i < 6; ++i) ewP *= ewP;          // ew^64
  float ca = 0.f, cb = 0.f;
#pragma unroll 4
  for (int s = 0; s < kSeg; ++s) {
    const size_t idx = ((size_t)b * kSeg + s) * kD + d;
    carA[idx] = ca;
    carB[idx] = cb;
    ca = ewP * ca + segA[idx];
    cb = ewP * cb + segB[idx];
  }
}

__global__ __launch_bounds__(256) void k_wkv_out(
    const unsigned short* __restrict__ kq, const unsigned short* __restrict__ vq,
    const unsigned short* __restrict__ rq, const float* __restrict__ td,
    const float* __restrict__ tf, const float* __restrict__ carA,
    const float* __restrict__ carB, unsigned short* __restrict__ out) {
  const int d = blockIdx.x * 256 + threadIdx.x;
  const int b = blockIdx.y;
  const int s = blockIdx.z;
  const float ew = __expf(-__expf(td[d]));
  const float uu = (s == 0) ? tf[d] : 0.f;
  const size_t base = ((size_t)b * kL + (size_t)s * kP) * kD + d;
  const size_t sidx = ((size_t)b * kSeg + s) * kD + d;
  float a = carA[sidx], bb = carB[sidx];
  unsigned short kA[16], vA[16], rA[16], kB[16], vB[16], rB[16];
  auto pref = [&](unsigned short* ka, unsigned short* va, unsigned short* ra, int c) {
    const size_t o0 = base + (size_t)c * 16 * kD;
#pragma unroll
    for (int j = 0; j < 16; ++j) {
      ka[j] = kq[o0 + (size_t)j * kD];
      va[j] = vq[o0 + (size_t)j * kD];
      ra[j] = rq[o0 + (size_t)j * kD];
    }
  };
  auto comp = [&](const unsigned short* ka, const unsigned short* va,
                  const unsigned short* ra, int c) {
    const size_t o0 = base + (size_t)c * 16 * kD;
#pragma unroll
    for (int j = 0; j < 16; ++j) {
      float kf = bf2f(ka[j]);
      if (s == 0 && c == 0 && j == 0) kf += uu;
      float ek = __expf(kf);
      a = ew * a + ek * bf2f(va[j]);
      bb = ew * bb + ek;
      float y = a / (bb + 1e-8f);
      float sr = 1.f / (1.f + __expf(-bf2f(ra[j])));
      out[o0 + (size_t)j * kD] = f2bf(sr * y);
    }
  };
  pref(kA, vA, rA, 0);
  pref(kB, vB, rB, 1); comp(kA, vA, rA, 0);
  pref(kA, vA, rA, 2); comp(kB, vB, rB, 1);
  pref(kB, vB, rB, 3); comp(kA, vA, rA, 2);
  comp(kB, vB, rB, 3);
}

// ====== gemmT: BM=BN=256 BK=64, 8 waves of 128x64, 16x16x32 (R8 loop, verified) ======
// Best-verified GEMM structure. Seven schedule/geometry variants all regressed:
// 3-deep LDS pipe (R5), 8-phase graft (R7), issue pins (R8-null), B-direct flat
// (R10) & blocked (R11, spills), 32x32 shape (R12, 4-way LDS conflicts),
// BK=32 2-blocks/CU (R14). Keep: T1 XCD bands, T2 XOR swizzle, T5 setprio,
// one barrier + lgkm(0) + vmcnt(0) per K-tile, counted vmcnt(8) prologue.
// EPI: 0 bf16 store, 1 bf16(addf + acc) [x1b], 2 relu(acc)^2, 3 sigmoid,
//      4 f32 store acc, 6 f32 addb(bf16) + mulb*(Cf+acc) [final combine]
template <int EPI>
__global__ __launch_bounds__(512, 2) void gemmT(
    const bf16_t* __restrict__ A0, long strA, int lda,
    const bf16_t* __restrict__ B0, long strB, int ldb,
    bf16_t* __restrict__ Cb0, float* __restrict__ Cf, long strC,
    int N, int K, int nbx,
    const float* __restrict__ addf, const bf16_t* __restrict__ addb,
    const bf16_t* __restrict__ mulb) {
  __shared__ __align__(16) char lds[131072];
  const int z = blockIdx.z;
  const bf16_t* A = A0 + (size_t)z * strA;
  const bf16_t* Bt = B0 + (size_t)z * strB;
  const int nwg = gridDim.x;
  const int wg = (blockIdx.x & 7) * (nwg >> 3) + (blockIdx.x >> 3);
  const int by = wg / nbx, bx = wg - by * nbx;
  const long brow = (long)by * 256;
  const long bcol = (long)bx * 256;
  const int tid = threadIdx.x;
  const int lane = tid & 63;
  const int wid = tid >> 6;
  const int wr = wid >> 2, wc = wid & 3;

  f32x4 acc[8][4] = {};

  const int trow = tid >> 3;
  const int scol = ((tid & 7) * 16) ^ ((trow & 7) << 4);
  const char* Ag = (const char*)(A + (brow + trow) * (size_t)lda) + scol;
  const char* Bg = (const char*)(Bt + (bcol + trow) * (size_t)ldb) + scol;
  const long rsA = 64L * lda * 2;
  const long rsB = 64L * ldb * 2;

#define STAGE(kt, p)                                   \
  {                                                    \
    const long kb = (long)(kt) * 128;                  \
    char* Ld = lds + (p) * 65536 + tid * 16;           \
    gld16(Ag + kb, Ld);                                \
    gld16(Ag + kb + rsA, Ld + 8192);                   \
    gld16(Ag + kb + 2 * rsA, Ld + 16384);              \
    gld16(Ag + kb + 3 * rsA, Ld + 24576);              \
    gld16(Bg + kb, Ld + 32768);                        \
    gld16(Bg + kb + rsB, Ld + 40960);                  \
    gld16(Bg + kb + 2 * rsB, Ld + 49152);              \
    gld16(Bg + kb + 3 * rsB, Ld + 57344);              \
  }

  const int l16 = lane & 15, kq = lane >> 4;
  const int swz = (l16 & 7) << 4;
  const int oS0 = (kq * 16) ^ swz;
  const int oS1 = (64 + kq * 16) ^ swz;
  const char* Arow = lds + (wr * 128 + l16) * 128;
  const char* Brow = lds + 32768 + (wc * 64 + l16) * 128;

  bf16x8 aE[8], bE[4], aO[8], bO[4];
  const int NT = K >> 6;

  STAGE(0, 0) STAGE(1, 1)
  asm volatile("s_waitcnt vmcnt(8)" ::: "memory");   // STAGE(0) landed (intrinsics ordered)
  __builtin_amdgcn_s_barrier();
#pragma unroll
  for (int m = 0; m < 8; ++m) aE[m] = *(const bf16x8*)(Arow + m * 2048 + oS0);
#pragma unroll
  for (int n = 0; n < 4; ++n) bE[n] = *(const bf16x8*)(Brow + n * 2048 + oS0);

  for (int t = 0; t < NT; ++t) {
    const int p = t & 1;
    const char* Ap = Arow + p * 65536;
    const char* Bp = Brow + p * 65536;
#pragma unroll
    for (int m = 0; m < 8; ++m) aO[m] = *(const bf16x8*)(Ap + m * 2048 + oS1);
#pragma unroll
    for (int n = 0; n < 4; ++n) bO[n] = *(const bf16x8*)(Bp + n * 2048 + oS1);
    __builtin_amdgcn_sched_barrier(0);
    __builtin_amdgcn_s_setprio(1);
#pragma unroll
    for (int m = 0; m < 8; ++m)
#pragma unroll
      for (int n = 0; n < 4; ++n)
        acc[m][n] = __builtin_amdgcn_mfma_f32_16x16x32_bf16(aE[m], bE[n], acc[m][n], 0, 0, 0);
    __builtin_amdgcn_s_setprio(0);
    asm volatile("s_waitcnt lgkmcnt(0)" ::: "memory");
    asm volatile("s_waitcnt vmcnt(0)" ::: "memory");
    __builtin_amdgcn_s_barrier();
    if (t + 2 < NT) STAGE(t + 2, p)
    if (t + 1 < NT) {
      const char* An = Arow + (1 - p) * 65536;
      const char* Bn = Brow + (1 - p) * 65536;
#pragma unroll
      for (int m = 0; m < 8; ++m) aE[m] = *(const bf16x8*)(An + m * 2048 + oS0);
#pragma unroll
      for (int n = 0; n < 4; ++n) bE[n] = *(const bf16x8*)(Bn + n * 2048 + oS0);
    }
    __builtin_amdgcn_sched_barrier(0);
    __builtin_amdgcn_s_setprio(1);
#pragma unroll
    for (int m = 0; m < 8; ++m)
#pragma unroll
      for (int n = 0; n < 4; ++n)
        acc[m][n] = __builtin_amdgcn_mfma_f32_16x16x32_bf16(aO[m], bO[n], acc[m][n], 0, 0, 0);
    __builtin_amdgcn_s_setprio(0);
  }
#undef STAGE

  bf16_t* Cb = Cb0 + (size_t)z * strC;
  const long orow = brow + wr * 128 + (lane >> 4) * 4;
  const long ocol = bcol + wc * 64 + l16;
#pragma unroll
  for (int m = 0; m < 8; ++m) {
#pragma unroll
    for (int reg = 0; reg < 4; ++reg) {
      const long r = orow + m * 16 + reg;
#pragma unroll
      for (int n = 0; n < 4; ++n) {
        const size_t idx = (size_t)r * N + ocol + n * 16;
        const float v = acc[m][n][reg];
        if constexpr (EPI == 0) {
          Cb[idx] = __float2bfloat16(v);
        } else if constexpr (EPI == 1) {
          Cb[idx] = __float2bfloat16(addf[idx] + v);
        } else if constexpr (EPI == 2) {
          float u = v > 0.f ? v : 0.f;
          Cb[idx] = __float2bfloat16(u * u);
        } else if constexpr (EPI == 3) {
          Cb[idx] = __float2bfloat16(1.f / (1.f + __expf(-v)));
        } else if constexpr (EPI == 4) {
          Cf[idx] = v;
        } else {
          Cf[idx] = __bfloat162float(addb[idx]) + __bfloat162float(mulb[idx]) * (Cf[idx] + v);
        }
      }
    }
  }
}

extern "C" void kernel_launch(void* const* d_in, const int* in_sizes, int n_in,
                              void* d_out, int out_size, void* d_ws, size_t ws_size,
                              hipStream_t stream) {
  const float* x    = (const float*)d_in[0];
  const float* ln1g = (const float*)d_in[1];
  const float* ln1b = (const float*)d_in[2];
  const float* Wk   = (const float*)d_in[3];
  const float* Wv   = (const float*)d_in[4];
  const float* Wr   = (const float*)d_in[5];
  const float* Wo   = (const float*)d_in[6];
  const float* td   = (const float*)d_in[7];
  const float* tf   = (const float*)d_in[8];
  const float* mk   = (const float*)d_in[9];
  const float* mv   = (const float*)d_in[10];
  const float* mr   = (const float*)d_in[11];
  const float* ln2g = (const float*)d_in[12];
  const float* ln2b = (const float*)d_in[13];
  const float* Wfk  = (const float*)d_in[14];
  const float* Wfv  = (const float*)d_in[15];
  const float* Wfr  = (const float*)d_in[16];

  char* ws = (char*)d_ws;
  const size_t MB = 1ull << 20;
  bf16_t* WkT  = (bf16_t*)(ws + 0 * MB);
  bf16_t* WvT  = (bf16_t*)(ws + 2 * MB);
  bf16_t* WrT  = (bf16_t*)(ws + 4 * MB);
  bf16_t* WoT  = (bf16_t*)(ws + 6 * MB);
  bf16_t* WfkT = (bf16_t*)(ws + 8 * MB);    // [4096][1024]
  bf16_t* WfvT = (bf16_t*)(ws + 16 * MB);   // [1024][4096]
  bf16_t* WfrT = (bf16_t*)(ws + 24 * MB);
  bf16_t* xk   = (bf16_t*)(ws + 28 * MB);
  bf16_t* xv   = (bf16_t*)(ws + 60 * MB);
  bf16_t* xr   = (bf16_t*)(ws + 92 * MB);
  bf16_t* kbuf = (bf16_t*)(ws + 124 * MB);
  bf16_t* vbuf = (bf16_t*)(ws + 156 * MB);
  bf16_t* rbuf = (bf16_t*)(ws + 188 * MB);
  float*  segA = (float*)(ws + 60 * MB);
  float*  segB = (float*)(ws + 61 * MB);
  float*  carA = (float*)(ws + 62 * MB);
  float*  carB = (float*)(ws + 63 * MB);
  bf16_t* rwkv = (bf16_t*)(ws + 92 * MB);
  bf16_t* x1b  = (bf16_t*)(ws + 28 * MB);   // bf16 residual, 32 MB
  bf16_t* rr   = (bf16_t*)(ws + 92 * MB);
  bf16_t* ynb  = (bf16_t*)(ws + 124 * MB);
  bf16_t* kk   = (bf16_t*)(ws + 124 * MB);  // [16384][2048] bf16 = 64 MB
  bf16_t* ymix = (bf16_t*)(ws + 188 * MB);
  float*  out  = (float*)d_out;
  const long sX = (long)kM * kD;
  const long sW = (long)kD * kD;

  dim3 blk(256), blkg(512);
  // weights -> bf16 B^T (five 1024^2 batched; Wfk/Wfv separate shapes)
  k_transpose5<<<dim3(32, 32, 5), blk, 0, stream>>>(Wk, Wv, Wr, Wo, Wfr,
                                                    WkT, WvT, WrT, WoT, WfrT);
  k_transpose_cast<<<dim3(128, 32), blk, 0, stream>>>(Wfk, WfkT, 1024, 4096);
  k_transpose_cast<<<dim3(32, 128), blk, 0, stream>>>(Wfv, WfvT, 4096, 1024);

  // ---- time mixing ----
  k_ln1f<<<kM, blk, 0, stream>>>(x, ln1g, ln1b, mk, mv, mr, xk, xv, xr);
  gemmT<0><<<dim3(256, 1, 3), blkg, 0, stream>>>(xk, sX, 1024, WkT, sW, 1024,
      kbuf, nullptr, sX, 1024, 1024, 4, nullptr, nullptr, nullptr);
  k_wkv_seg<<<dim3(4, 8, kSeg), blk, 0, stream>>>((const unsigned short*)kbuf,
      (const unsigned short*)vbuf, td, tf, segA, segB);
  k_wkv_carry<<<dim3(4, 8), blk, 0, stream>>>(td, segA, segB, carA, carB);
  k_wkv_out<<<dim3(4, 8, kSeg), blk, 0, stream>>>((const unsigned short*)kbuf,
      (const unsigned short*)vbuf, (const unsigned short*)rbuf, td, tf, carA, carB,
      (unsigned short*)rwkv);
  gemmT<1><<<256, blkg, 0, stream>>>(rwkv, 0, 1024, WoT, 0, 1024,
      x1b, nullptr, 0, 1024, 1024, 4, x, nullptr, nullptr);

  // ---- channel mixing ----
  k_ln2fb<<<kM, blk, 0, stream>>>(x1b, ln2g, ln2b, ymix, ynb);
  gemmT<3><<<256, blkg, 0, stream>>>(ynb, 0, 1024, WfrT, 0, 1024,
      rr, nullptr, 0, 1024, 1024, 4, nullptr, nullptr, nullptr);
  // hidden dim in 2 chunks of 2048: kk = relu(ymix@Wfk[:,c])^2; out (+)= kk@Wfv[c,:]
  for (int c = 0; c < 2; ++c) {
    gemmT<2><<<512, blkg, 0, stream>>>(ymix, 0, 1024, WfkT + (size_t)c * 2048 * 1024, 0, 1024,
        kk, nullptr, 0, 2048, 1024, 8, nullptr, nullptr, nullptr);
    if (c == 0)
      gemmT<4><<<256, blkg, 0, stream>>>(kk, 0, 2048, WfvT + 0, 0, 4096,
          nullptr, out, 0, 1024, 2048, 4, nullptr, nullptr, nullptr);
    else
      gemmT<6><<<256, blkg, 0, stream>>>(kk, 0, 2048, WfvT + 2048, 0, 4096,
          nullptr, out, 0, 1024, 2048, 4, nullptr, x1b, rr);
  }
}

// Round 16
// 609.013 us; speedup vs baseline: 1.0651x; 1.0176x over previous
//
#include <hip/hip_runtime.h>
#include <hip/hip_bf16.h>
#include <stdint.h>

typedef __hip_bfloat16 bf16_t;
typedef __attribute__((ext_vector_type(8))) short bf16x8;   // 8 bf16 = 4 VGPR
typedef __attribute__((ext_vector_type(4))) float f32x4;

#define DEV static __device__ __forceinline__

constexpr int kBB = 8, kL = 2048, kD = 1024;
constexpr int kM = kBB * kL;   // 16384 rows
constexpr int kSeg = 32, kP = 64;   // WKV: 32 segments x 64 steps

DEV float bf2f(unsigned short u) { return __uint_as_float((unsigned)u << 16); }
DEV unsigned short f2bf(float f) {
  unsigned u = __float_as_uint(f);
  return (unsigned short)((u + 0x7fffu + ((u >> 16) & 1u)) >> 16);  // RNE
}

// async global->LDS, 16B per lane. LDS dest is wave-uniform-base + lane*16.
DEV void gld16(const void* g, void* l) {
  const __attribute__((address_space(1))) unsigned* gp =
      (const __attribute__((address_space(1))) unsigned*)(uintptr_t)g;
  __attribute__((address_space(3))) unsigned* lp =
      (__attribute__((address_space(3))) unsigned*)(unsigned)(uintptr_t)l;
  __builtin_amdgcn_global_load_lds(gp, lp, 16, 0, 0);
}

// ------- batched weight transpose + cast (five 1024x1024): W[R][C] f32 -> Wt[C][R] bf16 -------
__global__ __launch_bounds__(256) void k_transpose5(
    const float* __restrict__ W0, const float* __restrict__ W1, const float* __restrict__ W2,
    const float* __restrict__ W3, const float* __restrict__ W4,
    bf16_t* __restrict__ T0, bf16_t* __restrict__ T1, bf16_t* __restrict__ T2,
    bf16_t* __restrict__ T3, bf16_t* __restrict__ T4) {
  const float* W; bf16_t* Wt;
  switch (blockIdx.z) {
    case 0: W = W0; Wt = T0; break;
    case 1: W = W1; Wt = T1; break;
    case 2: W = W2; Wt = T2; break;
    case 3: W = W3; Wt = T3; break;
    default: W = W4; Wt = T4; break;
  }
  __shared__ float tile[32][33];
  const int bx = blockIdx.x * 32, by = blockIdx.y * 32;
  const int tx = threadIdx.x & 31, ty = threadIdx.x >> 5;
#pragma unroll
  for (int i = 0; i < 32; i += 8)
    tile[ty + i][tx] = W[(size_t)(by + ty + i) * 1024 + (bx + tx)];
  __syncthreads();
#pragma unroll
  for (int i = 0; i < 32; i += 8)
    Wt[(size_t)(bx + ty + i) * 1024 + (by + tx)] = __float2bfloat16(tile[tx][ty + i]);
}

// ---------------- weight transpose + cast: W[R][C] f32 -> Wt[C][R] bf16 ---------------
__global__ __launch_bounds__(256) void k_transpose_cast(
    const float* __restrict__ W, bf16_t* __restrict__ Wt, int R, int C) {
  __shared__ float tile[32][33];
  const int bx = blockIdx.x * 32;
  const int by = blockIdx.y * 32;
  const int tx = threadIdx.x & 31, ty = threadIdx.x >> 5;
#pragma unroll
  for (int i = 0; i < 32; i += 8)
    tile[ty + i][tx] = W[(size_t)(by + ty + i) * C + (bx + tx)];
  __syncthreads();
#pragma unroll
  for (int i = 0; i < 32; i += 8)
    Wt[(size_t)(bx + ty + i) * R + (by + tx)] = __float2bfloat16(tile[tx][ty + i]);
}

// -------- fused LN(+stats)+shift+time-mix -> xk/xv/xr (bf16); one block per row --------
__global__ __launch_bounds__(256) void k_ln1f(
    const float* __restrict__ X, const float* __restrict__ g, const float* __restrict__ be,
    const float* __restrict__ mk, const float* __restrict__ mv, const float* __restrict__ mr,
    bf16_t* __restrict__ ok, bf16_t* __restrict__ ov, bf16_t* __restrict__ orr) {
  const int row = blockIdx.x;
  const int l = row & (kL - 1);
  const int i = threadIdx.x;                 // 4 floats per thread
  const bool hp = (l != 0);
  float xa[4], pa[4] = {0.f, 0.f, 0.f, 0.f};
  *(float4*)xa = ((const float4*)(X + (size_t)row * kD))[i];
  if (hp) *(float4*)pa = ((const float4*)(X + (size_t)(row - 1) * kD))[i];
  float s0 = xa[0] + xa[1] + xa[2] + xa[3];
  float q0 = xa[0] * xa[0] + xa[1] * xa[1] + xa[2] * xa[2] + xa[3] * xa[3];
  float s1 = pa[0] + pa[1] + pa[2] + pa[3];
  float q1 = pa[0] * pa[0] + pa[1] * pa[1] + pa[2] * pa[2] + pa[3] * pa[3];
#pragma unroll
  for (int off = 32; off > 0; off >>= 1) {
    s0 += __shfl_xor(s0, off); q0 += __shfl_xor(q0, off);
    s1 += __shfl_xor(s1, off); q1 += __shfl_xor(q1, off);
  }
  __shared__ float red[4][4];
  const int wid = i >> 6, lane = i & 63;
  if (lane == 0) { red[wid][0] = s0; red[wid][1] = q0; red[wid][2] = s1; red[wid][3] = q1; }
  __syncthreads();
  s0 = red[0][0] + red[1][0] + red[2][0] + red[3][0];
  q0 = red[0][1] + red[1][1] + red[2][1] + red[3][1];
  s1 = red[0][2] + red[1][2] + red[2][2] + red[3][2];
  q1 = red[0][3] + red[1][3] + red[2][3] + red[3][3];
  const float m0 = s0 * (1.f / kD);
  const float r0 = rsqrtf(fmaxf(q0 * (1.f / kD) - m0 * m0, 0.f) + 1e-5f);
  const float m1 = s1 * (1.f / kD);
  const float r1 = rsqrtf(fmaxf(q1 * (1.f / kD) - m1 * m1, 0.f) + 1e-5f);
  float ga[4], ba[4], ka[4], va[4], ra[4];
  *(float4*)ga = ((const float4*)g)[i];
  *(float4*)ba = ((const float4*)be)[i];
  *(float4*)ka = ((const float4*)mk)[i];
  *(float4*)va = ((const float4*)mv)[i];
  *(float4*)ra = ((const float4*)mr)[i];
  ushort4 uk, uv, ur;
  unsigned short* pk = (unsigned short*)&uk;
  unsigned short* pv = (unsigned short*)&uv;
  unsigned short* pr = (unsigned short*)&ur;
#pragma unroll
  for (int c = 0; c < 4; ++c) {
    float xn = (xa[c] - m0) * r0 * ga[c] + ba[c];
    float xp = hp ? (pa[c] - m1) * r1 * ga[c] + ba[c] : 0.f;   // shift: row 0 -> zeros
    pk[c] = f2bf(xn * ka[c] + xp * (1.f - ka[c]));
    pv[c] = f2bf(xn * va[c] + xp * (1.f - va[c]));
    pr[c] = f2bf(xn * ra[c] + xp * (1.f - ra[c]));
  }
  ((ushort4*)(ok + (size_t)row * kD))[i] = uk;
  ((ushort4*)(ov + (size_t)row * kD))[i] = uv;
  ((ushort4*)(orr + (size_t)row * kD))[i] = ur;
}

// ---- fused LN(+stats)+shift for channel mix, bf16 input x1: ymix=0.5(yn+yp), ynb=yn ----
__global__ __launch_bounds__(256) void k_ln2fb(
    const bf16_t* __restrict__ X, const float* __restrict__ g, const float* __restrict__ be,
    bf16_t* __restrict__ om, bf16_t* __restrict__ on) {
  const int row = blockIdx.x;
  const int l = row & (kL - 1);
  const int i = threadIdx.x;
  const bool hp = (l != 0);
  ushort4 xu = ((const ushort4*)(X + (size_t)row * kD))[i];
  ushort4 pu = make_ushort4(0, 0, 0, 0);
  if (hp) pu = ((const ushort4*)(X + (size_t)(row - 1) * kD))[i];
  float xa[4], pa[4];
  xa[0] = bf2f(xu.x); xa[1] = bf2f(xu.y); xa[2] = bf2f(xu.z); xa[3] = bf2f(xu.w);
  pa[0] = bf2f(pu.x); pa[1] = bf2f(pu.y); pa[2] = bf2f(pu.z); pa[3] = bf2f(pu.w);
  float s0 = xa[0] + xa[1] + xa[2] + xa[3];
  float q0 = xa[0] * xa[0] + xa[1] * xa[1] + xa[2] * xa[2] + xa[3] * xa[3];
  float s1 = pa[0] + pa[1] + pa[2] + pa[3];
  float q1 = pa[0] * pa[0] + pa[1] * pa[1] + pa[2] * pa[2] + pa[3] * pa[3];
#pragma unroll
  for (int off = 32; off > 0; off >>= 1) {
    s0 += __shfl_xor(s0, off); q0 += __shfl_xor(q0, off);
    s1 += __shfl_xor(s1, off); q1 += __shfl_xor(q1, off);
  }
  __shared__ float red[4][4];
  const int wid = i >> 6, lane = i & 63;
  if (lane == 0) { red[wid][0] = s0; red[wid][1] = q0; red[wid][2] = s1; red[wid][3] = q1; }
  __syncthreads();
  s0 = red[0][0] + red[1][0] + red[2][0] + red[3][0];
  q0 = red[0][1] + red[1][1] + red[2][1] + red[3][1];
  s1 = red[0][2] + red[1][2] + red[2][2] + red[3][2];
  q1 = red[0][3] + red[1][3] + red[2][3] + red[3][3];
  const float m0 = s0 * (1.f / kD);
  const float r0 = rsqrtf(fmaxf(q0 * (1.f / kD) - m0 * m0, 0.f) + 1e-5f);
  const float m1 = s1 * (1.f / kD);
  const float r1 = rsqrtf(fmaxf(q1 * (1.f / kD) - m1 * m1, 0.f) + 1e-5f);
  float ga[4], ba[4];
  *(float4*)ga = ((const float4*)g)[i];
  *(float4*)ba = ((const float4*)be)[i];
  ushort4 um, un;
  unsigned short* qm = (unsigned short*)&um;
  unsigned short* qn = (unsigned short*)&un;
#pragma unroll
  for (int c = 0; c < 4; ++c) {
    float yn = (xa[c] - m0) * r0 * ga[c] + ba[c];
    float yp = hp ? (pa[c] - m1) * r1 * ga[c] + ba[c] : 0.f;
    qm[c] = f2bf(0.5f * (yn + yp));
    qn[c] = f2bf(yn);
  }
  ((ushort4*)(om + (size_t)row * kD))[i] = um;
  ((ushort4*)(on + (size_t)row * kD))[i] = un;
}

// ===================== WKV: segmented parallel scan over L =====================
__global__ __launch_bounds__(256) void k_wkv_seg(
    const unsigned short* __restrict__ kq, const unsigned short* __restrict__ vq,
    const float* __restrict__ td, const float* __restrict__ tf,
    float* __restrict__ segA, float* __restrict__ segB) {
  const int d = blockIdx.x * 256 + threadIdx.x;
  const int b = blockIdx.y;
  const int s = blockIdx.z;
  const float ew = __expf(-__expf(td[d]));
  const float uu = (s == 0) ? tf[d] : 0.f;
  const size_t base = ((size_t)b * kL + (size_t)s * kP) * kD + d;
  float a = 0.f, bb = 0.f;
  unsigned short kA[16], vA[16], kB[16], vB[16];
  auto pref = [&](unsigned short* ka, unsigned short* va, int c) {
    const size_t o0 = base + (size_t)c * 16 * kD;
#pragma unroll
    for (int j = 0; j < 16; ++j) {
      ka[j] = kq[o0 + (size_t)j * kD];
      va[j] = vq[o0 + (size_t)j * kD];
    }
  };
  auto comp = [&](const unsigned short* ka, const unsigned short* va, int c) {
#pragma unroll
    for (int j = 0; j < 16; ++j) {
      float kf = bf2f(ka[j]);
      if (s == 0 && c == 0 && j == 0) kf += uu;    // t==0: exp(u + k0)
      float ek = __expf(kf);
      a = ew * a + ek * bf2f(va[j]);
      bb = ew * bb + ek;
    }
  };
  pref(kA, vA, 0);
  pref(kB, vB, 1); comp(kA, vA, 0);
  pref(kA, vA, 2); comp(kB, vB, 1);
  pref(kB, vB, 3); comp(kA, vA, 2);
  comp(kB, vB, 3);
  const size_t sidx = ((size_t)b * kSeg + s) * kD + d;
  segA[sidx] = a;
  segB[sidx] = bb;
}

__global__ __launch_bounds__(256) void k_wkv_carry(
    const float* __restrict__ td,
    const float* __restrict__ segA, const float* __restrict__ segB,
    float* __restrict__ carA, float* __restrict__ carB) {
  const int d = blockIdx.x * 256 + threadIdx.x;
  const int b = blockIdx.y;
  const float ew = __expf(-__expf(td[d]));
  float ewP = ew;
#pragma unroll
  for (int i = 0; i < 6; ++i) ewP *= ewP;          // ew^64
  float ca = 0.f, cb = 0.f;
#pragma unroll 4
  for (int s = 0; s < kSeg; ++s) {
    const size_t idx = ((size_t)b * kSeg + s) * kD + d;
    carA[idx] = ca;
    carB[idx] = cb;
    ca = ewP * ca + segA[idx];
    cb = ewP * cb + segB[idx];
  }
}

__global__ __launch_bounds__(256) void k_wkv_out(
    const unsigned short* __restrict__ kq, const unsigned short* __restrict__ vq,
    const unsigned short* __restrict__ rq, const float* __restrict__ td,
    const float* __restrict__ tf, const float* __restrict__ carA,
    const float* __restrict__ carB, unsigned short* __restrict__ out) {
  const int d = blockIdx.x * 256 + threadIdx.x;
  const int b = blockIdx.y;
  const int s = blockIdx.z;
  const float ew = __expf(-__expf(td[d]));
  const float uu = (s == 0) ? tf[d] : 0.f;
  const size_t base = ((size_t)b * kL + (size_t)s * kP) * kD + d;
  const size_t sidx = ((size_t)b * kSeg + s) * kD + d;
  float a = carA[sidx], bb = carB[sidx];
  unsigned short kA[16], vA[16], rA[16], kB[16], vB[16], rB[16];
  auto pref = [&](unsigned short* ka, unsigned short* va, unsigned short* ra, int c) {
    const size_t o0 = base + (size_t)c * 16 * kD;
#pragma unroll
    for (int j = 0; j < 16; ++j) {
      ka[j] = kq[o0 + (size_t)j * kD];
      va[j] = vq[o0 + (size_t)j * kD];
      ra[j] = rq[o0 + (size_t)j * kD];
    }
  };
  auto comp = [&](const unsigned short* ka, const unsigned short* va,
                  const unsigned short* ra, int c) {
    const size_t o0 = base + (size_t)c * 16 * kD;
#pragma unroll
    for (int j = 0; j < 16; ++j) {
      float kf = bf2f(ka[j]);
      if (s == 0 && c == 0 && j == 0) kf += uu;
      float ek = __expf(kf);
      a = ew * a + ek * bf2f(va[j]);
      bb = ew * bb + ek;
      float y = a / (bb + 1e-8f);
      float sr = 1.f / (1.f + __expf(-bf2f(ra[j])));
      out[o0 + (size_t)j * kD] = f2bf(sr * y);
    }
  };
  pref(kA, vA, rA, 0);
  pref(kB, vB, rB, 1); comp(kA, vA, rA, 0);
  pref(kA, vA, rA, 2); comp(kB, vB, rB, 1);
  pref(kB, vB, rB, 3); comp(kA, vA, rA, 2);
  comp(kB, vB, rB, 3);
}

// ====== gemmT: BM=BN=256 BK=64, 8 waves of 128x64, 16x16x32; fine-grain interleave ======
// R15 base (verified 619us) with ONE change: inside each half-tile cluster, the
// 12 LDS reads (or 8 gld16 stages) are interleaved 3-reads/8-MFMA in 4 groups,
// pinned by sched_barrier(0) at group boundaries. No extra barriers or waits.
// Rationale: measured per-tile = LDS(2800cyc) + MFMA(2483cyc) SERIAL because all
// 8 waves burst-issue reads then burst-MFMA (R8 analysis); fine alternation keeps
// both pipes fed. Sync skeleton unchanged: one barrier + lgkm(0) + vmcnt(0)/tile.
template <int EPI>
__global__ __launch_bounds__(512, 2) void gemmT(
    const bf16_t* __restrict__ A0, long strA, int lda,
    const bf16_t* __restrict__ B0, long strB, int ldb,
    bf16_t* __restrict__ Cb0, float* __restrict__ Cf, long strC,
    int N, int K, int nbx,
    const float* __restrict__ addf, const bf16_t* __restrict__ addb,
    const bf16_t* __restrict__ mulb) {
  __shared__ __align__(16) char lds[131072];
  const int z = blockIdx.z;
  const bf16_t* A = A0 + (size_t)z * strA;
  const bf16_t* Bt = B0 + (size_t)z * strB;
  const int nwg = gridDim.x;
  const int wg = (blockIdx.x & 7) * (nwg >> 3) + (blockIdx.x >> 3);
  const int by = wg / nbx, bx = wg - by * nbx;
  const long brow = (long)by * 256;
  const long bcol = (long)bx * 256;
  const int tid = threadIdx.x;
  const int lane = tid & 63;
  const int wid = tid >> 6;
  const int wr = wid >> 2, wc = wid & 3;

  f32x4 acc[8][4] = {};

  const int trow = tid >> 3;
  const int scol = ((tid & 7) * 16) ^ ((trow & 7) << 4);
  const char* Ag = (const char*)(A + (brow + trow) * (size_t)lda) + scol;
  const char* Bg = (const char*)(Bt + (bcol + trow) * (size_t)ldb) + scol;
  const long rsA = 64L * lda * 2;
  const long rsB = 64L * ldb * 2;

#define STAGE(kt, p)                                   \
  {                                                    \
    const long kb = (long)(kt) * 128;                  \
    char* Ld = lds + (p) * 65536 + tid * 16;           \
    gld16(Ag + kb, Ld);                                \
    gld16(Ag + kb + rsA, Ld + 8192);                   \
    gld16(Ag + kb + 2 * rsA, Ld + 16384);              \
    gld16(Ag + kb + 3 * rsA, Ld + 24576);              \
    gld16(Bg + kb, Ld + 32768);                        \
    gld16(Bg + kb + rsB, Ld + 40960);                  \
    gld16(Bg + kb + 2 * rsB, Ld + 49152);              \
    gld16(Bg + kb + 3 * rsB, Ld + 57344);              \
  }

  const int l16 = lane & 15, kq = lane >> 4;
  const int swz = (l16 & 7) << 4;
  const int oS0 = (kq * 16) ^ swz;
  const int oS1 = (64 + kq * 16) ^ swz;
  const char* Arow = lds + (wr * 128 + l16) * 128;
  const char* Brow = lds + 32768 + (wc * 64 + l16) * 128;

  bf16x8 aE[8], bE[4], aO[8], bO[4];
  const int NT = K >> 6;

  STAGE(0, 0) STAGE(1, 1)
  asm volatile("s_waitcnt vmcnt(8)" ::: "memory");   // STAGE(0) landed (intrinsics ordered)
  __builtin_amdgcn_s_barrier();
#pragma unroll
  for (int m = 0; m < 8; ++m) aE[m] = *(const bf16x8*)(Arow + m * 2048 + oS0);
#pragma unroll
  for (int n = 0; n < 4; ++n) bE[n] = *(const bf16x8*)(Brow + n * 2048 + oS0);

  for (int t = 0; t < NT; ++t) {
    const int p = t & 1;
    const char* Ap = Arow + p * 65536;
    const char* Bp = Brow + p * 65536;
    // ---- half 1: interleave {3 reads of slice1} with {8 MFMA of slice0} x4 ----
#pragma unroll
    for (int g = 0; g < 4; ++g) {
      aO[2 * g] = *(const bf16x8*)(Ap + (2 * g) * 2048 + oS1);
      aO[2 * g + 1] = *(const bf16x8*)(Ap + (2 * g + 1) * 2048 + oS1);
      bO[g] = *(const bf16x8*)(Bp + g * 2048 + oS1);
      __builtin_amdgcn_sched_barrier(0);
      __builtin_amdgcn_s_setprio(1);
#pragma unroll
      for (int n = 0; n < 4; ++n) {
        acc[2 * g][n] = __builtin_amdgcn_mfma_f32_16x16x32_bf16(aE[2 * g], bE[n], acc[2 * g][n], 0, 0, 0);
        acc[2 * g + 1][n] = __builtin_amdgcn_mfma_f32_16x16x32_bf16(aE[2 * g + 1], bE[n], acc[2 * g + 1][n], 0, 0, 0);
      }
      __builtin_amdgcn_s_setprio(0);
      __builtin_amdgcn_sched_barrier(0);
    }
    asm volatile("s_waitcnt lgkmcnt(0)" ::: "memory");   // my reads of buf p done
    asm volatile("s_waitcnt vmcnt(0)" ::: "memory");     // STAGE(t+1) landed (1 tile old)
    __builtin_amdgcn_s_barrier();                        // p free to overwrite; 1-p ready
    // ---- half 2: interleave {3 reads of next tile + 2 stage gld16} with {8 MFMA slice1} x4 ----
    {
      const bool rd = (t + 1 < NT);
      const bool st = (t + 2 < NT);
      const char* An = Arow + (1 - p) * 65536;
      const char* Bn = Brow + (1 - p) * 65536;
      const long kb2 = (long)(t + 2) * 128;
      char* Ld2 = lds + p * 65536 + tid * 16;
#pragma unroll
      for (int g = 0; g < 4; ++g) {
        if (rd) {
          aE[2 * g] = *(const bf16x8*)(An + (2 * g) * 2048 + oS0);
          aE[2 * g + 1] = *(const bf16x8*)(An + (2 * g + 1) * 2048 + oS0);
          bE[g] = *(const bf16x8*)(Bn + g * 2048 + oS0);
        }
        if (st) {
          if (g == 0) { gld16(Ag + kb2, Ld2); gld16(Ag + kb2 + rsA, Ld2 + 8192); }
          else if (g == 1) { gld16(Ag + kb2 + 2 * rsA, Ld2 + 16384); gld16(Ag + kb2 + 3 * rsA, Ld2 + 24576); }
          else if (g == 2) { gld16(Bg + kb2, Ld2 + 32768); gld16(Bg + kb2 + rsB, Ld2 + 40960); }
          else { gld16(Bg + kb2 + 2 * rsB, Ld2 + 49152); gld16(Bg + kb2 + 3 * rsB, Ld2 + 57344); }
        }
        __builtin_amdgcn_sched_barrier(0);
        __builtin_amdgcn_s_setprio(1);
#pragma unroll
        for (int n = 0; n < 4; ++n) {
          acc[2 * g][n] = __builtin_amdgcn_mfma_f32_16x16x32_bf16(aO[2 * g], bO[n], acc[2 * g][n], 0, 0, 0);
          acc[2 * g + 1][n] = __builtin_amdgcn_mfma_f32_16x16x32_bf16(aO[2 * g + 1], bO[n], acc[2 * g + 1][n], 0, 0, 0);
        }
        __builtin_amdgcn_s_setprio(0);
        __builtin_amdgcn_sched_barrier(0);
      }
    }
  }
#undef STAGE

  bf16_t* Cb = Cb0 + (size_t)z * strC;
  const long orow = brow + wr * 128 + (lane >> 4) * 4;
  const long ocol = bcol + wc * 64 + l16;
#pragma unroll
  for (int m = 0; m < 8; ++m) {
#pragma unroll
    for (int reg = 0; reg < 4; ++reg) {
      const long r = orow + m * 16 + reg;
#pragma unroll
      for (int n = 0; n < 4; ++n) {
        const size_t idx = (size_t)r * N + ocol + n * 16;
        const float v = acc[m][n][reg];
        if constexpr (EPI == 0) {
          Cb[idx] = __float2bfloat16(v);
        } else if constexpr (EPI == 1) {
          Cb[idx] = __float2bfloat16(addf[idx] + v);
        } else if constexpr (EPI == 2) {
          float u = v > 0.f ? v : 0.f;
          Cb[idx] = __float2bfloat16(u * u);
        } else if constexpr (EPI == 3) {
          Cb[idx] = __float2bfloat16(1.f / (1.f + __expf(-v)));
        } else if constexpr (EPI == 4) {
          Cf[idx] = v;
        } else {
          Cf[idx] = __bfloat162float(addb[idx]) + __bfloat162float(mulb[idx]) * (Cf[idx] + v);
        }
      }
    }
  }
}

extern "C" void kernel_launch(void* const* d_in, const int* in_sizes, int n_in,
                              void* d_out, int out_size, void* d_ws, size_t ws_size,
                              hipStream_t stream) {
  const float* x    = (const float*)d_in[0];
  const float* ln1g = (const float*)d_in[1];
  const float* ln1b = (const float*)d_in[2];
  const float* Wk   = (const float*)d_in[3];
  const float* Wv   = (const float*)d_in[4];
  const float* Wr   = (const float*)d_in[5];
  const float* Wo   = (const float*)d_in[6];
  const float* td   = (const float*)d_in[7];
  const float* tf   = (const float*)d_in[8];
  const float* mk   = (const float*)d_in[9];
  const float* mv   = (const float*)d_in[10];
  const float* mr   = (const float*)d_in[11];
  const float* ln2g = (const float*)d_in[12];
  const float* ln2b = (const float*)d_in[13];
  const float* Wfk  = (const float*)d_in[14];
  const float* Wfv  = (const float*)d_in[15];
  const float* Wfr  = (const float*)d_in[16];

  char* ws = (char*)d_ws;
  const size_t MB = 1ull << 20;
  bf16_t* WkT  = (bf16_t*)(ws + 0 * MB);
  bf16_t* WvT  = (bf16_t*)(ws + 2 * MB);
  bf16_t* WrT  = (bf16_t*)(ws + 4 * MB);
  bf16_t* WoT  = (bf16_t*)(ws + 6 * MB);
  bf16_t* WfkT = (bf16_t*)(ws + 8 * MB);    // [4096][1024]
  bf16_t* WfvT = (bf16_t*)(ws + 16 * MB);   // [1024][4096]
  bf16_t* WfrT = (bf16_t*)(ws + 24 * MB);
  bf16_t* xk   = (bf16_t*)(ws + 28 * MB);
  bf16_t* xv   = (bf16_t*)(ws + 60 * MB);
  bf16_t* xr   = (bf16_t*)(ws + 92 * MB);
  bf16_t* kbuf = (bf16_t*)(ws + 124 * MB);
  bf16_t* vbuf = (bf16_t*)(ws + 156 * MB);
  bf16_t* rbuf = (bf16_t*)(ws + 188 * MB);
  float*  segA = (float*)(ws + 60 * MB);
  float*  segB = (float*)(ws + 61 * MB);
  float*  carA = (float*)(ws + 62 * MB);
  float*  carB = (float*)(ws + 63 * MB);
  bf16_t* rwkv = (bf16_t*)(ws + 92 * MB);
  bf16_t* x1b  = (bf16_t*)(ws + 28 * MB);   // bf16 residual, 32 MB
  bf16_t* rr   = (bf16_t*)(ws + 92 * MB);
  bf16_t* ynb  = (bf16_t*)(ws + 124 * MB);
  bf16_t* kk   = (bf16_t*)(ws + 124 * MB);  // [16384][2048] bf16 = 64 MB
  bf16_t* ymix = (bf16_t*)(ws + 188 * MB);
  float*  out  = (float*)d_out;
  const long sX = (long)kM * kD;
  const long sW = (long)kD * kD;

  dim3 blk(256), blkg(512);
  // weights -> bf16 B^T (five 1024^2 batched; Wfk/Wfv separate shapes)
  k_transpose5<<<dim3(32, 32, 5), blk, 0, stream>>>(Wk, Wv, Wr, Wo, Wfr,
                                                    WkT, WvT, WrT, WoT, WfrT);
  k_transpose_cast<<<dim3(128, 32), blk, 0, stream>>>(Wfk, WfkT, 1024, 4096);
  k_transpose_cast<<<dim3(32, 128), blk, 0, stream>>>(Wfv, WfvT, 4096, 1024);

  // ---- time mixing ----
  k_ln1f<<<kM, blk, 0, stream>>>(x, ln1g, ln1b, mk, mv, mr, xk, xv, xr);
  gemmT<0><<<dim3(256, 1, 3), blkg, 0, stream>>>(xk, sX, 1024, WkT, sW, 1024,
      kbuf, nullptr, sX, 1024, 1024, 4, nullptr, nullptr, nullptr);
  k_wkv_seg<<<dim3(4, 8, kSeg), blk, 0, stream>>>((const unsigned short*)kbuf,
      (const unsigned short*)vbuf, td, tf, segA, segB);
  k_wkv_carry<<<dim3(4, 8), blk, 0, stream>>>(td, segA, segB, carA, carB);
  k_wkv_out<<<dim3(4, 8, kSeg), blk, 0, stream>>>((const unsigned short*)kbuf,
      (const unsigned short*)vbuf, (const unsigned short*)rbuf, td, tf, carA, carB,
      (unsigned short*)rwkv);
  gemmT<1><<<256, blkg, 0, stream>>>(rwkv, 0, 1024, WoT, 0, 1024,
      x1b, nullptr, 0, 1024, 1024, 4, x, nullptr, nullptr);

  // ---- channel mixing ----
  k_ln2fb<<<kM, blk, 0, stream>>>(x1b, ln2g, ln2b, ymix, ynb);
  gemmT<3><<<256, blkg, 0, stream>>>(ynb, 0, 1024, WfrT, 0, 1024,
      rr, nullptr, 0, 1024, 1024, 4, nullptr, nullptr, nullptr);
  // hidden dim in 2 chunks of 2048: kk = relu(ymix@Wfk[:,c])^2; out (+)= kk@Wfv[c,:]
  for (int c = 0; c < 2; ++c) {
    gemmT<2><<<512, blkg, 0, stream>>>(ymix, 0, 1024, WfkT + (size_t)c * 2048 * 1024, 0, 1024,
        kk, nullptr, 0, 2048, 1024, 8, nullptr, nullptr, nullptr);
    if (c == 0)
      gemmT<4><<<256, blkg, 0, stream>>>(kk, 0, 2048, WfvT + 0, 0, 4096,
          nullptr, out, 0, 1024, 2048, 4, nullptr, nullptr, nullptr);
    else
      gemmT<6><<<256, blkg, 0, stream>>>(kk, 0, 2048, WfvT + 2048, 0, 4096,
          nullptr, out, 0, 1024, 2048, 4, nullptr, x1b, rr);
  }
}